// Round 4
// baseline (339.839 us; speedup 1.0000x reference)
//
#include <hip/hip_runtime.h>

// ---------------------------------------------------------------------------
// MemoryAttention: B=2 Q=1024 K=2048 M=1024 E=1024 H=32 HD=32
// Pipeline:
//   prep  : fp32 -> bf16, panel-major XOR-swizzled layout for GEMM staging
//           dst[(kt*R+row)*64 + (c^(row&7))*8 + j] = src[row][kt*64+c*8+j]
//   gemm  : m97-style tile, BK=64, global_load_lds(16B), swizzled ds_read_b128
//   qp    = (query Wq^T + bq) * SCALE * LOG2E      (bf16 row-major)
//   kcat  = concat(key,mem) Wk^T + bk              (bf16 row-major)
//   vcat  = concat(value,mem) Wv^T + bv            (bf16 row-major)
//   vT    = per-(b,h) transpose of vcat, key axis pi-permuted
//   attn  = softmax(qp kcat^T) vcat  -> written swizzled panel-major
//   out   = attn Wo^T + bo                         (fp32 -> d_out)
// attn: 4 waves/block split the 3072 keys; max-free softmax => partials are
// plain sums; row-sums via MFMA with all-ones B fragment; combine in LDS.
// ---------------------------------------------------------------------------

typedef float  f32x4  __attribute__((ext_vector_type(4)));
typedef short  bf16x8 __attribute__((ext_vector_type(8)));
typedef unsigned int   u32;
typedef unsigned short u16;
typedef u32 u32x2 __attribute__((ext_vector_type(2)));
typedef u32 u32x4 __attribute__((ext_vector_type(4)));
typedef u16 u16x4 __attribute__((ext_vector_type(4)));

#define SCALE_  0.17677669529663687f   // 32^-0.5
#define LOG2E_  1.4426950408889634f

// raw v_exp_f32 (scores are |s|<~5: no denorm/inf handling needed)
#if defined(__has_builtin)
#  if __has_builtin(__builtin_amdgcn_exp2f)
#    define EXP2F(x) __builtin_amdgcn_exp2f(x)
#  endif
#endif
#ifndef EXP2F
#  define EXP2F(x) __builtin_exp2f(x)
#endif

static __device__ __forceinline__ u32 bfpack2(float lo, float hi) {
  u32 a = __builtin_bit_cast(u32, lo) + 0x8000u;
  u32 b = __builtin_bit_cast(u32, hi) + 0x8000u;
  return __builtin_amdgcn_perm(b, a, 0x07060302u);
}
static __device__ __forceinline__ u16 bf16of(float x) {
  return (u16)((__builtin_bit_cast(u32, x) + 0x8000u) >> 16);
}
static __device__ __forceinline__ void gld_lds16(const u16* g, u16* l) {
  __builtin_amdgcn_global_load_lds(
      (const __attribute__((address_space(1))) void*)g,
      (__attribute__((address_space(3))) void*)l, 16, 0, 0);
}

// ---------------------------------------------------------------------------
// prep: fp32 -> bf16 swizzled panel-major. kt-major / row-minor mapping:
// each iteration writes 4 KB fully contiguous per 256 threads.
// ---------------------------------------------------------------------------
__global__ __launch_bounds__(256)
void prep_kernel(const float* __restrict__ q, const float* __restrict__ k,
                 const float* __restrict__ v, const float* __restrict__ m,
                 const float* __restrict__ wq, const float* __restrict__ wk,
                 const float* __restrict__ wv, const float* __restrict__ wo,
                 u16* qs, u16* ks, u16* vs, u16* ms,
                 u16* wqs, u16* wks, u16* wvs, u16* wos) {
  const int bid = blockIdx.x;
  const float* src; u16* dst; int R, r0;
  if (bid < 32)       { src = q;  dst = qs;  R = 2048; r0 = bid * 64; }
  else if (bid < 96)  { src = k;  dst = ks;  R = 4096; r0 = (bid - 32) * 64; }
  else if (bid < 160) { src = v;  dst = vs;  R = 4096; r0 = (bid - 96) * 64; }
  else if (bid < 192) { src = m;  dst = ms;  R = 2048; r0 = (bid - 160) * 64; }
  else if (bid < 208) { src = wq; dst = wqs; R = 1024; r0 = (bid - 192) * 64; }
  else if (bid < 224) { src = wk; dst = wks; R = 1024; r0 = (bid - 208) * 64; }
  else if (bid < 240) { src = wv; dst = wvs; R = 1024; r0 = (bid - 224) * 64; }
  else                { src = wo; dst = wos; R = 1024; r0 = (bid - 240) * 64; }

  for (int i = 0; i < 32; ++i) {
    const int idx = i * 256 + threadIdx.x;    // 0..8191 = 16 kt x 64 rows x 8 c
    const int kt  = idx >> 9;
    const int rem = idx & 511;
    const int row = rem >> 3;
    const int c   = rem & 7;
    const float* s = src + (size_t)(r0 + row) * 1024 + kt * 64 + c * 8;
    f32x4 a = *(const f32x4*)s, b = *(const f32x4*)(s + 4);
    u32x4 p;
    p.x = bfpack2(a.x, a.y); p.y = bfpack2(a.z, a.w);
    p.z = bfpack2(b.x, b.y); p.w = bfpack2(b.z, b.w);
    *(u32x4*)&dst[((size_t)kt * R + r0 + row) * 64 + ((c ^ (row & 7)) << 3)] = p;
  }
}

// ---------------------------------------------------------------------------
// GEMM: C[m,n] = (sum_k A[m,k]*W[n,k] + bias[n]) * scale
// A from two per-batch segments (panel-major swizzled, strides R0/R1).
// MT x 128 tile, BK=64, 4 waves (2x2), global_load_lds staging.
// ---------------------------------------------------------------------------
template <int MT, int OUT_BF16>
__global__ __launch_bounds__(256)
void gemm_sw_kernel(const u16* __restrict__ A0, int L0, int R0,
                    const u16* __restrict__ A1, int L1, int R1,
                    const u16* __restrict__ Wsw,
                    const float* __restrict__ bias,
                    void* __restrict__ Cout, float scale) {
  constexpr int MI = MT / 32;          // mi frags per wave
  __shared__ u16 As[MT * 64];
  __shared__ u16 Bs[128 * 64];

  const int tid  = threadIdx.x;
  const int lane = tid & 63;
  const int wave = tid >> 6;
  const int ln   = lane & 15;
  const int quad = lane >> 4;
  const int wm   = wave >> 1;
  const int wn   = wave & 1;
  const int bm = blockIdx.x, bn = blockIdx.y;

  const int gr0 = bm * MT;
  const int per = L0 + L1;
  const int bb  = gr0 / per;
  const int i0  = gr0 - bb * per;
  const u16* Abase; size_t row0; int RA;
  if (i0 < L0) { Abase = A0; row0 = (size_t)bb * L0 + i0; RA = R0; }
  else         { Abase = A1; row0 = (size_t)bb * L1 + (i0 - L0); RA = R1; }

  f32x4 acc[MI][4];
#pragma unroll
  for (int i = 0; i < MI; ++i)
#pragma unroll
    for (int j = 0; j < 4; ++j)
      acc[i][j] = (f32x4){0.f, 0.f, 0.f, 0.f};

  for (int kt = 0; kt < 16; ++kt) {
    const u16* Ag = Abase + ((size_t)kt * RA + row0) * 64;
    const u16* Bg = Wsw + ((size_t)kt * 1024 + bn * 128) * 64;
#pragma unroll
    for (int r = 0; r < MI; ++r) {
      const int ii = wave * MI + r;
      gld_lds16(Ag + ii * 512 + lane * 8, &As[ii * 512]);
    }
#pragma unroll
    for (int r = 0; r < 4; ++r) {
      const int ii = wave * 4 + r;
      gld_lds16(Bg + ii * 512 + lane * 8, &Bs[ii * 512]);
    }
    __syncthreads();

#pragma unroll
    for (int kk = 0; kk < 2; ++kk) {
      bf16x8 af[MI], bfr[4];
#pragma unroll
      for (int mi = 0; mi < MI; ++mi) {
        const int row = wm * (MI * 16) + mi * 16 + ln;
        af[mi] = *(const bf16x8*)&As[row * 64 + (((kk * 4 + quad) ^ (ln & 7)) << 3)];
      }
#pragma unroll
      for (int ni = 0; ni < 4; ++ni) {
        const int row = wn * 64 + ni * 16 + ln;
        bfr[ni] = *(const bf16x8*)&Bs[row * 64 + (((kk * 4 + quad) ^ (ln & 7)) << 3)];
      }
#pragma unroll
      for (int mi = 0; mi < MI; ++mi)
#pragma unroll
        for (int ni = 0; ni < 4; ++ni)
          acc[mi][ni] = __builtin_amdgcn_mfma_f32_16x16x32_bf16(af[mi], bfr[ni], acc[mi][ni], 0, 0, 0);
    }
    __syncthreads();
  }

  // epilogue: C/D layout col=lane&15, row=quad*4+reg
#pragma unroll
  for (int ni = 0; ni < 4; ++ni) {
    const int gc = bn * 128 + wn * 64 + ni * 16 + ln;
    const float bval = bias[gc];
#pragma unroll
    for (int mi = 0; mi < MI; ++mi) {
      const int gr = bm * MT + wm * (MI * 16) + mi * 16 + quad * 4;
#pragma unroll
      for (int r = 0; r < 4; ++r) {
        const float vv = (acc[mi][ni][r] + bval) * scale;
        if (OUT_BF16)
          ((u16*)Cout)[(size_t)(gr + r) * 1024 + gc] = bf16of(vv);
        else
          ((float*)Cout)[(size_t)(gr + r) * 1024 + gc] = vv;
      }
    }
  }
}

// ---------------------------------------------------------------------------
// Transpose vcat (b*3072+l, h*32+d) -> vT[(b,h,d), chunk-permuted l]
// pi within each 64-key chunk: pi(lc) = (lc&15)*4 + (lc>>4).
// ---------------------------------------------------------------------------
__global__ __launch_bounds__(256)
void transpose_v_kernel(const u16* __restrict__ vcat, u16* __restrict__ vT) {
  __shared__ u16 T[32][132];
  const int tid = threadIdx.x;
  const int l0  = blockIdx.x * 128;
  const int bh  = blockIdx.y;
  const int b   = bh >> 5, h = bh & 31;

#pragma unroll
  for (int j = 0; j < 4; ++j) {
    const int c = tid + 256 * j;
    const int row  = c >> 3;
    const int col4 = (c & 7) * 4;
    u16x4 v = *(const u16x4*)&vcat[(size_t)(b * 3072 + l0 + row) * 1024 + h * 32 + col4];
    T[col4 + 0][row] = v.x; T[col4 + 1][row] = v.y;
    T[col4 + 2][row] = v.z; T[col4 + 3][row] = v.w;
  }
  __syncthreads();
#pragma unroll
  for (int j = 0; j < 4; ++j) {
    const int c = tid + 256 * j;
    const int d   = c >> 5;
    const int rem = c & 31;
    const int ch  = rem >> 4;
    const int x   = rem & 15;
    u16x4 v;
    v.x = T[d][ch * 64 + x +  0];
    v.y = T[d][ch * 64 + x + 16];
    v.z = T[d][ch * 64 + x + 32];
    v.w = T[d][ch * 64 + x + 48];
    *(u16x4*)&vT[(size_t)(bh * 32 + d) * 3072 + l0 + ch * 64 + x * 4] = v;
  }
}

// ---------------------------------------------------------------------------
// Attention: block = (bh, 32 q-rows), 4 waves split the 3072 keys (12 chunks
// of 64). Max-free softmax (scores pre-scaled by SCALE*LOG2E in qp).
// Raw v_exp_f32; pointer-increment K/V loads; rowsum via all-ones MFMA.
// 8 blocks/CU (LDS 18432 B x 8 = 147 KB, VGPR<=64) -> 32 waves/CU TLP.
// Grid: bid = qt*64 + bh  =>  XCD = bid%8 = bh%8 (L2-pins K/V per XCD).
// ---------------------------------------------------------------------------
__global__ __launch_bounds__(256, 8)
void attn_kernel(const u16* __restrict__ qp,
                 const u16* __restrict__ kcat,
                 const u16* __restrict__ vTp,
                 u16* __restrict__ attn_sw) {
  __shared__ u16 PwAll[4 * 32 * 72];     // 18432 B; reused for combine

  const int tid  = threadIdx.x;
  const int lane = tid & 63;
  const int wave = tid >> 6;
  const int ln   = lane & 15;
  const int quad = lane >> 4;
  const int bid  = blockIdx.x;
  const int bh   = bid & 63;
  const int qt   = bid >> 6;
  const int b    = bh >> 5;
  const int h    = bh & 31;
  const int q0   = qt * 32;

  bf16x8 qf[2];
#pragma unroll
  for (int mf = 0; mf < 2; ++mf)
    qf[mf] = *(const bf16x8*)&qp[(size_t)(b * 1024 + q0 + mf * 16 + ln) * 1024 + h * 32 + quad * 8];

  f32x4 acc[2][2], accS[2];
#pragma unroll
  for (int mf = 0; mf < 2; ++mf) {
    accS[mf] = (f32x4){0.f, 0.f, 0.f, 0.f};
#pragma unroll
    for (int df = 0; df < 2; ++df) acc[mf][df] = (f32x4){0.f, 0.f, 0.f, 0.f};
  }
  bf16x8 ones;
#pragma unroll
  for (int i = 0; i < 8; ++i) ones[i] = (short)0x3F80;   // bf16 1.0

  const u16* kbase = kcat + (size_t)(b * 3072) * 1024 + h * 32;
  const u16* vbase = vTp + (size_t)(bh * 32) * 3072;
  u16* Pw = &PwAll[wave * (32 * 72)];

  // persistent pointers, bumped by constants each chunk
  const u16* kp[4];
  const u16* vp[2];
#pragma unroll
  for (int nf = 0; nf < 4; ++nf)
    kp[nf] = kbase + (size_t)(wave * 768 + nf * 16 + ln) * 1024 + quad * 8;
#pragma unroll
  for (int df = 0; df < 2; ++df)
    vp[df] = vbase + (size_t)(df * 16 + ln) * 3072 + wave * 768 + quad * 8;

  for (int ci = 0; ci < 12; ++ci) {
    bf16x8 kf[4], vf[4];
#pragma unroll
    for (int nf = 0; nf < 4; ++nf)
      kf[nf] = *(const bf16x8*)kp[nf];
#pragma unroll
    for (int kk = 0; kk < 2; ++kk)
#pragma unroll
      for (int df = 0; df < 2; ++df)
        vf[kk * 2 + df] = *(const bf16x8*)(vp[df] + kk * 32);

    // S = Q K^T
    f32x4 s[2][4];
#pragma unroll
    for (int mf = 0; mf < 2; ++mf)
#pragma unroll
      for (int nf = 0; nf < 4; ++nf)
        s[mf][nf] = __builtin_amdgcn_mfma_f32_16x16x32_bf16(qf[mf], kf[nf],
                                                            (f32x4){0.f, 0.f, 0.f, 0.f}, 0, 0, 0);

    // P = exp2(S), pi-packed into LDS (b64 writes, stride 72)
#pragma unroll
    for (int mf = 0; mf < 2; ++mf)
#pragma unroll
      for (int r = 0; r < 4; ++r) {
        const float p0 = EXP2F(s[mf][0][r]);
        const float p1 = EXP2F(s[mf][1][r]);
        const float p2 = EXP2F(s[mf][2][r]);
        const float p3 = EXP2F(s[mf][3][r]);
        u32x2 pk;
        pk.x = bfpack2(p0, p1);
        pk.y = bfpack2(p2, p3);
        *(u32x2*)&Pw[(mf * 16 + quad * 4 + r) * 72 + ln * 4] = pk;
      }

    // O += P V ; rowsum += P * ones  (within-wave LDS write->read)
#pragma unroll
    for (int kk = 0; kk < 2; ++kk)
#pragma unroll
      for (int mf = 0; mf < 2; ++mf) {
        bf16x8 pf = *(const bf16x8*)&Pw[(mf * 16 + ln) * 72 + kk * 32 + quad * 8];
        accS[mf] = __builtin_amdgcn_mfma_f32_16x16x32_bf16(pf, ones, accS[mf], 0, 0, 0);
#pragma unroll
        for (int df = 0; df < 2; ++df)
          acc[mf][df] = __builtin_amdgcn_mfma_f32_16x16x32_bf16(pf, vf[kk * 2 + df], acc[mf][df], 0, 0, 0);
      }

#pragma unroll
    for (int nf = 0; nf < 4; ++nf) kp[nf] += 64 * 1024;
#pragma unroll
    for (int df = 0; df < 2; ++df) vp[df] += 64;
  }

  // ---- cross-wave combine ----
  __syncthreads();
  f32x4* CA = (f32x4*)PwAll;             // [w][mf][df][lane] : 16 KB
  f32x4* CS = (f32x4*)&PwAll[8192];      // [w][mf][quad]     : 512 B
#pragma unroll
  for (int mf = 0; mf < 2; ++mf) {
#pragma unroll
    for (int df = 0; df < 2; ++df)
      CA[((wave * 2 + mf) * 2 + df) * 64 + lane] = acc[mf][df];
    if (ln == 0) CS[(wave * 2 + mf) * 4 + quad] = accS[mf];
  }
  __syncthreads();

  if (wave == 0) {
    const int j = ln & 7, chi = ln >> 3;
#pragma unroll
    for (int mf = 0; mf < 2; ++mf) {
      f32x4 l = CS[(0 + mf) * 4 + quad];
#pragma unroll
      for (int w = 1; w < 4; ++w) l += CS[((w * 2) + mf) * 4 + quad];
      f32x4 inv;
#pragma unroll
      for (int r = 0; r < 4; ++r) inv[r] = 1.0f / l[r];
#pragma unroll
      for (int df = 0; df < 2; ++df) {
        f32x4 t = CA[((0 + mf) * 2 + df) * 64 + lane];
#pragma unroll
        for (int w = 1; w < 4; ++w) t += CA[(((w * 2) + mf) * 2 + df) * 64 + lane];
        const int c = (h & 1) * 4 + df * 2 + chi;
#pragma unroll
        for (int r = 0; r < 4; ++r) {
          const int row = b * 1024 + q0 + mf * 16 + quad * 4 + r;
          const int cp  = c ^ ((quad * 4 + r) & 7);
          attn_sw[((size_t)(h >> 1) * 2048 + row) * 64 + cp * 8 + j] = bf16of(t[r] * inv[r]);
        }
      }
    }
  }
}

// ---------------------------------------------------------------------------
extern "C" void kernel_launch(void* const* d_in, const int* in_sizes, int n_in,
                              void* d_out, int out_size, void* d_ws, size_t ws_size,
                              hipStream_t stream) {
  (void)in_sizes; (void)n_in; (void)out_size; (void)ws_size;
  const float* query  = (const float*)d_in[0];
  const float* key    = (const float*)d_in[1];
  const float* value  = (const float*)d_in[2];
  const float* memory = (const float*)d_in[3];
  const float* Wq = (const float*)d_in[4];
  const float* bq = (const float*)d_in[5];
  const float* Wk = (const float*)d_in[6];
  const float* bk = (const float*)d_in[7];
  const float* Wv = (const float*)d_in[8];
  const float* bv = (const float*)d_in[9];
  const float* Wo = (const float*)d_in[10];
  const float* bo = (const float*)d_in[11];
  float* out = (float*)d_out;

  // workspace layout (76 MB)
  char* ws = (char*)d_ws;
  const size_t MB = 1024 * 1024;
  u16* query_sw = (u16*)(ws + 0 * MB);    //  4 MB (2048 rows)
  u16* key_sw   = (u16*)(ws + 4 * MB);    //  8 MB (4096 rows)
  u16* value_sw = (u16*)(ws + 12 * MB);   //  8 MB (4096 rows)
  u16* mem_sw   = (u16*)(ws + 20 * MB);   //  4 MB (2048 rows)
  u16* Wq_sw    = (u16*)(ws + 24 * MB);   //  2 MB
  u16* Wk_sw    = (u16*)(ws + 26 * MB);   //  2 MB
  u16* Wv_sw    = (u16*)(ws + 28 * MB);   //  2 MB
  u16* Wo_sw    = (u16*)(ws + 30 * MB);   //  2 MB
  u16* qp       = (u16*)(ws + 32 * MB);   //  4 MB
  u16* kcat     = (u16*)(ws + 36 * MB);   // 12 MB
  u16* vcat     = (u16*)(ws + 48 * MB);   // 12 MB
  u16* vT       = (u16*)(ws + 60 * MB);   // 12 MB
  u16* attn_sw  = (u16*)(ws + 72 * MB);   //  4 MB

  dim3 blk(256);
  prep_kernel<<<dim3(256), blk, 0, stream>>>(query, key, value, memory, Wq, Wk, Wv, Wo,
                                             query_sw, key_sw, value_sw, mem_sw,
                                             Wq_sw, Wk_sw, Wv_sw, Wo_sw);
  // qp = (query Wq^T + bq) * SCALE * LOG2E
  gemm_sw_kernel<64, 1><<<dim3(32, 8), blk, 0, stream>>>(
      query_sw, 2048, 2048, nullptr, 0, 0, Wq_sw, bq, qp, SCALE_ * LOG2E_);
  // kcat = concat(key, memory) Wk^T + bk
  gemm_sw_kernel<128, 1><<<dim3(48, 8), blk, 0, stream>>>(
      key_sw, 2048, 4096, mem_sw, 1024, 2048, Wk_sw, bk, kcat, 1.0f);
  // vcat = concat(value, memory) Wv^T + bv
  gemm_sw_kernel<128, 1><<<dim3(48, 8), blk, 0, stream>>>(
      value_sw, 2048, 4096, mem_sw, 1024, 2048, Wv_sw, bv, vcat, 1.0f);
  // vT (pi-permuted) for PV B-operand
  transpose_v_kernel<<<dim3(24, 64), blk, 0, stream>>>(vcat, vT);
  // attention -> swizzled panel-major A for final GEMM
  attn_kernel<<<dim3(2048), blk, 0, stream>>>(qp, kcat, vT, attn_sw);
  // out = attn Wo^T + bo
  gemm_sw_kernel<64, 0><<<dim3(32, 8), blk, 0, stream>>>(
      attn_sw, 2048, 2048, nullptr, 0, 0, Wo_sw, bo, (void*)out, 1.0f);
}

// Round 5
// 282.922 us; speedup vs baseline: 1.2012x; 1.2012x over previous
//
#include <hip/hip_runtime.h>

// ---------------------------------------------------------------------------
// MemoryAttention: B=2 Q=1024 K=2048 M=1024 E=1024 H=32 HD=32
// Pipeline (6 launches):
//   prep  : fp32 -> bf16, panel-major XOR-swizzled layout for GEMM staging
//   proj3 : ONE launch = {qp, kcat, vcat} 128x128-tile GEMMs (block-dispatch)
//   vT    : per-(b,h) transpose of vcat, key axis pi-permuted
//   attn  : softmax(qp kcat^T) vcat -> swizzled panel-major
//   out   : attn Wo^T + bo (fp32 -> d_out)
// attn: 4 waves/block split the 3072 keys; max-free softmax => partials are
// plain sums; row-sums via MFMA with all-ones B fragment; combine in LDS.
// launch_bounds(256,6): 6 blocks/CU (LDS 110KB, VGPR cap ~85 - NO spills;
// (256,8) in round 4 forced VGPR=32 -> 47MB scratch writes, 243MB fetch).
// ---------------------------------------------------------------------------

typedef float  f32x4  __attribute__((ext_vector_type(4)));
typedef short  bf16x8 __attribute__((ext_vector_type(8)));
typedef unsigned int   u32;
typedef unsigned short u16;
typedef u32 u32x2 __attribute__((ext_vector_type(2)));
typedef u32 u32x4 __attribute__((ext_vector_type(4)));
typedef u16 u16x4 __attribute__((ext_vector_type(4)));

#define SCALE_  0.17677669529663687f   // 32^-0.5
#define LOG2E_  1.4426950408889634f

// raw v_exp_f32 (scores are |s|<~5: no denorm/inf handling needed)
#if defined(__has_builtin)
#  if __has_builtin(__builtin_amdgcn_exp2f)
#    define EXP2F(x) __builtin_amdgcn_exp2f(x)
#  endif
#endif
#ifndef EXP2F
#  define EXP2F(x) __builtin_exp2f(x)
#endif

static __device__ __forceinline__ u32 bfpack2(float lo, float hi) {
  u32 a = __builtin_bit_cast(u32, lo) + 0x8000u;
  u32 b = __builtin_bit_cast(u32, hi) + 0x8000u;
  return __builtin_amdgcn_perm(b, a, 0x07060302u);
}
static __device__ __forceinline__ u16 bf16of(float x) {
  return (u16)((__builtin_bit_cast(u32, x) + 0x8000u) >> 16);
}
static __device__ __forceinline__ void gld_lds16(const u16* g, u16* l) {
  __builtin_amdgcn_global_load_lds(
      (const __attribute__((address_space(1))) void*)g,
      (__attribute__((address_space(3))) void*)l, 16, 0, 0);
}

// ---------------------------------------------------------------------------
// prep: fp32 -> bf16 swizzled panel-major. kt-major / row-minor mapping:
// each iteration writes 4 KB fully contiguous per 256 threads.
// ---------------------------------------------------------------------------
__global__ __launch_bounds__(256)
void prep_kernel(const float* __restrict__ q, const float* __restrict__ k,
                 const float* __restrict__ v, const float* __restrict__ m,
                 const float* __restrict__ wq, const float* __restrict__ wk,
                 const float* __restrict__ wv, const float* __restrict__ wo,
                 u16* qs, u16* ks, u16* vs, u16* ms,
                 u16* wqs, u16* wks, u16* wvs, u16* wos) {
  const int bid = blockIdx.x;
  const float* src; u16* dst; int R, r0;
  if (bid < 32)       { src = q;  dst = qs;  R = 2048; r0 = bid * 64; }
  else if (bid < 96)  { src = k;  dst = ks;  R = 4096; r0 = (bid - 32) * 64; }
  else if (bid < 160) { src = v;  dst = vs;  R = 4096; r0 = (bid - 96) * 64; }
  else if (bid < 192) { src = m;  dst = ms;  R = 2048; r0 = (bid - 160) * 64; }
  else if (bid < 208) { src = wq; dst = wqs; R = 1024; r0 = (bid - 192) * 64; }
  else if (bid < 224) { src = wk; dst = wks; R = 1024; r0 = (bid - 208) * 64; }
  else if (bid < 240) { src = wv; dst = wvs; R = 1024; r0 = (bid - 224) * 64; }
  else                { src = wo; dst = wos; R = 1024; r0 = (bid - 240) * 64; }

  for (int i = 0; i < 32; ++i) {
    const int idx = i * 256 + threadIdx.x;    // 16 kt x 64 rows x 8 c
    const int kt  = idx >> 9;
    const int rem = idx & 511;
    const int row = rem >> 3;
    const int c   = rem & 7;
    const float* s = src + (size_t)(r0 + row) * 1024 + kt * 64 + c * 8;
    f32x4 a = *(const f32x4*)s, b = *(const f32x4*)(s + 4);
    u32x4 p;
    p.x = bfpack2(a.x, a.y); p.y = bfpack2(a.z, a.w);
    p.z = bfpack2(b.x, b.y); p.w = bfpack2(b.z, b.w);
    *(u32x4*)&dst[((size_t)kt * R + r0 + row) * 64 + ((c ^ (row & 7)) << 3)] = p;
  }
}

// ---------------------------------------------------------------------------
// Shared GEMM tile body: C[m,n] = (sum_k A[m,k]*W[n,k] + bias[n]) * scale
// MT x 128 tile, BK=64, 4 waves (2x2), global_load_lds staging, swizzled LDS.
// Abase/row0/RA already segment-resolved by the caller.
// ---------------------------------------------------------------------------
template <int MT, int OUT_BF16>
static __device__ __forceinline__
void gemm_tile(const u16* __restrict__ Abase, size_t row0, int RA,
               const u16* __restrict__ Wsw, const float* __restrict__ bias,
               void* __restrict__ Cout, float scale,
               int bm, int bn, u16* As, u16* Bs) {
  constexpr int MI = MT / 32;
  const int tid  = threadIdx.x;
  const int lane = tid & 63;
  const int wave = tid >> 6;
  const int ln   = lane & 15;
  const int quad = lane >> 4;
  const int wm   = wave >> 1;
  const int wn   = wave & 1;

  f32x4 acc[MI][4];
#pragma unroll
  for (int i = 0; i < MI; ++i)
#pragma unroll
    for (int j = 0; j < 4; ++j)
      acc[i][j] = (f32x4){0.f, 0.f, 0.f, 0.f};

  for (int kt = 0; kt < 16; ++kt) {
    const u16* Ag = Abase + ((size_t)kt * RA + row0) * 64;
    const u16* Bg = Wsw + ((size_t)kt * 1024 + bn * 128) * 64;
#pragma unroll
    for (int r = 0; r < MI; ++r) {
      const int ii = wave * MI + r;
      gld_lds16(Ag + ii * 512 + lane * 8, &As[ii * 512]);
    }
#pragma unroll
    for (int r = 0; r < 4; ++r) {
      const int ii = wave * 4 + r;
      gld_lds16(Bg + ii * 512 + lane * 8, &Bs[ii * 512]);
    }
    __syncthreads();

#pragma unroll
    for (int kk = 0; kk < 2; ++kk) {
      bf16x8 af[MI], bfr[4];
#pragma unroll
      for (int mi = 0; mi < MI; ++mi) {
        const int row = wm * (MI * 16) + mi * 16 + ln;
        af[mi] = *(const bf16x8*)&As[row * 64 + (((kk * 4 + quad) ^ (ln & 7)) << 3)];
      }
#pragma unroll
      for (int ni = 0; ni < 4; ++ni) {
        const int row = wn * 64 + ni * 16 + ln;
        bfr[ni] = *(const bf16x8*)&Bs[row * 64 + (((kk * 4 + quad) ^ (ln & 7)) << 3)];
      }
#pragma unroll
      for (int mi = 0; mi < MI; ++mi)
#pragma unroll
        for (int ni = 0; ni < 4; ++ni)
          acc[mi][ni] = __builtin_amdgcn_mfma_f32_16x16x32_bf16(af[mi], bfr[ni], acc[mi][ni], 0, 0, 0);
    }
    __syncthreads();
  }

  // epilogue: C/D layout col=lane&15, row=quad*4+reg
#pragma unroll
  for (int ni = 0; ni < 4; ++ni) {
    const int gc = bn * 128 + wn * 64 + ni * 16 + ln;
    const float bval = bias[gc];
#pragma unroll
    for (int mi = 0; mi < MI; ++mi) {
      const int gr = bm * MT + wm * (MI * 16) + mi * 16 + quad * 4;
#pragma unroll
      for (int r = 0; r < 4; ++r) {
        const float vv = (acc[mi][ni][r] + bval) * scale;
        if (OUT_BF16)
          ((u16*)Cout)[(size_t)(gr + r) * 1024 + gc] = bf16of(vv);
        else
          ((float*)Cout)[(size_t)(gr + r) * 1024 + gc] = vv;
      }
    }
  }
}

// ---------------------------------------------------------------------------
// proj3: one launch for qp (16 bm), kcat (48 bm), vcat (48 bm); grid (112, 8)
// ---------------------------------------------------------------------------
__global__ __launch_bounds__(256)
void proj3_kernel(const u16* __restrict__ query_sw,
                  const u16* __restrict__ key_sw,
                  const u16* __restrict__ value_sw,
                  const u16* __restrict__ mem_sw,
                  const u16* __restrict__ Wq_sw, const float* __restrict__ bq,
                  const u16* __restrict__ Wk_sw, const float* __restrict__ bk,
                  const u16* __restrict__ Wv_sw, const float* __restrict__ bv,
                  u16* qp, u16* kcat, u16* vcat) {
  __shared__ u16 As[128 * 64];
  __shared__ u16 Bs[128 * 64];
  const int bx = blockIdx.x, bn = blockIdx.y;

  const u16* Abase; size_t row0; int RA, bm;
  const u16* W; const float* bias; u16* C; float scale;

  if (bx < 16) {                      // qp = query Wq^T + bq, pre-scaled
    bm = bx; Abase = query_sw; row0 = (size_t)bm * 128; RA = 2048;
    W = Wq_sw; bias = bq; C = qp; scale = SCALE_ * LOG2E_;
  } else {
    const int bxx = (bx < 64) ? (bx - 16) : (bx - 64);
    bm = bxx;
    const int gr0 = bxx * 128;
    const int bb  = gr0 / 3072;
    const int i0  = gr0 - bb * 3072;
    const u16* seq = (bx < 64) ? key_sw : value_sw;
    if (i0 < 2048) { Abase = seq;    row0 = (size_t)bb * 2048 + i0;        RA = 4096; }
    else           { Abase = mem_sw; row0 = (size_t)bb * 1024 + (i0 - 2048); RA = 2048; }
    if (bx < 64) { W = Wk_sw; bias = bk; C = kcat; }
    else         { W = Wv_sw; bias = bv; C = vcat; }
    scale = 1.0f;
  }
  gemm_tile<128, 1>(Abase, row0, RA, W, bias, C, scale, bm, bn, As, Bs);
}

// ---------------------------------------------------------------------------
// out = attn Wo^T + bo  (fp32 out)
// ---------------------------------------------------------------------------
__global__ __launch_bounds__(256)
void gemm_out_kernel(const u16* __restrict__ attn_sw,
                     const u16* __restrict__ Wo_sw,
                     const float* __restrict__ bo,
                     float* __restrict__ out) {
  __shared__ u16 As[64 * 64];
  __shared__ u16 Bs[128 * 64];
  gemm_tile<64, 0>(attn_sw, (size_t)blockIdx.x * 64, 2048, Wo_sw, bo,
                   (void*)out, 1.0f, blockIdx.x, blockIdx.y, As, Bs);
}

// ---------------------------------------------------------------------------
// Transpose vcat (b*3072+l, h*32+d) -> vT[(b,h,d), chunk-permuted l]
// pi within each 64-key chunk: pi(lc) = (lc&15)*4 + (lc>>4).
// ---------------------------------------------------------------------------
__global__ __launch_bounds__(256)
void transpose_v_kernel(const u16* __restrict__ vcat, u16* __restrict__ vT) {
  __shared__ u16 T[32][132];
  const int tid = threadIdx.x;
  const int l0  = blockIdx.x * 128;
  const int bh  = blockIdx.y;
  const int b   = bh >> 5, h = bh & 31;

#pragma unroll
  for (int j = 0; j < 4; ++j) {
    const int c = tid + 256 * j;
    const int row  = c >> 3;
    const int col4 = (c & 7) * 4;
    u16x4 v = *(const u16x4*)&vcat[(size_t)(b * 3072 + l0 + row) * 1024 + h * 32 + col4];
    T[col4 + 0][row] = v.x; T[col4 + 1][row] = v.y;
    T[col4 + 2][row] = v.z; T[col4 + 3][row] = v.w;
  }
  __syncthreads();
#pragma unroll
  for (int j = 0; j < 4; ++j) {
    const int c = tid + 256 * j;
    const int d   = c >> 5;
    const int rem = c & 31;
    const int ch  = rem >> 4;
    const int x   = rem & 15;
    u16x4 v;
    v.x = T[d][ch * 64 + x +  0];
    v.y = T[d][ch * 64 + x + 16];
    v.z = T[d][ch * 64 + x + 32];
    v.w = T[d][ch * 64 + x + 48];
    *(u16x4*)&vT[(size_t)(bh * 32 + d) * 3072 + l0 + ch * 64 + x * 4] = v;
  }
}

// ---------------------------------------------------------------------------
// Attention: block = (bh, 32 q-rows), 4 waves split the 3072 keys (12 chunks
// of 64). Max-free softmax (scores pre-scaled by SCALE*LOG2E in qp).
// Raw v_exp_f32; pointer-increment K/V loads; rowsum via all-ones MFMA.
// 6 blocks/CU (LDS 110 KB, VGPR cap ~85 -> no scratch spills).
// Grid: bid = qt*64 + bh  =>  XCD = bid%8 = bh%8 (L2-pins K/V per XCD).
// ---------------------------------------------------------------------------
__global__ __launch_bounds__(256, 6)
void attn_kernel(const u16* __restrict__ qp,
                 const u16* __restrict__ kcat,
                 const u16* __restrict__ vTp,
                 u16* __restrict__ attn_sw) {
  __shared__ u16 PwAll[4 * 32 * 72];     // 18432 B; reused for combine

  const int tid  = threadIdx.x;
  const int lane = tid & 63;
  const int wave = tid >> 6;
  const int ln   = lane & 15;
  const int quad = lane >> 4;
  const int bid  = blockIdx.x;
  const int bh   = bid & 63;
  const int qt   = bid >> 6;
  const int b    = bh >> 5;
  const int h    = bh & 31;
  const int q0   = qt * 32;

  bf16x8 qf[2];
#pragma unroll
  for (int mf = 0; mf < 2; ++mf)
    qf[mf] = *(const bf16x8*)&qp[(size_t)(b * 1024 + q0 + mf * 16 + ln) * 1024 + h * 32 + quad * 8];

  f32x4 acc[2][2], accS[2];
#pragma unroll
  for (int mf = 0; mf < 2; ++mf) {
    accS[mf] = (f32x4){0.f, 0.f, 0.f, 0.f};
#pragma unroll
    for (int df = 0; df < 2; ++df) acc[mf][df] = (f32x4){0.f, 0.f, 0.f, 0.f};
  }
  bf16x8 ones;
#pragma unroll
  for (int i = 0; i < 8; ++i) ones[i] = (short)0x3F80;   // bf16 1.0

  const u16* kbase = kcat + (size_t)(b * 3072) * 1024 + h * 32;
  const u16* vbase = vTp + (size_t)(bh * 32) * 3072;
  u16* Pw = &PwAll[wave * (32 * 72)];

  // persistent pointers, bumped by constants each chunk
  const u16* kp[4];
  const u16* vp[2];
#pragma unroll
  for (int nf = 0; nf < 4; ++nf)
    kp[nf] = kbase + (size_t)(wave * 768 + nf * 16 + ln) * 1024 + quad * 8;
#pragma unroll
  for (int df = 0; df < 2; ++df)
    vp[df] = vbase + (size_t)(df * 16 + ln) * 3072 + wave * 768 + quad * 8;

  for (int ci = 0; ci < 12; ++ci) {
    bf16x8 kf[4], vf[4];
#pragma unroll
    for (int nf = 0; nf < 4; ++nf)
      kf[nf] = *(const bf16x8*)kp[nf];
#pragma unroll
    for (int kk = 0; kk < 2; ++kk)
#pragma unroll
      for (int df = 0; df < 2; ++df)
        vf[kk * 2 + df] = *(const bf16x8*)(vp[df] + kk * 32);

    // S = Q K^T
    f32x4 s[2][4];
#pragma unroll
    for (int mf = 0; mf < 2; ++mf)
#pragma unroll
      for (int nf = 0; nf < 4; ++nf)
        s[mf][nf] = __builtin_amdgcn_mfma_f32_16x16x32_bf16(qf[mf], kf[nf],
                                                            (f32x4){0.f, 0.f, 0.f, 0.f}, 0, 0, 0);

    // P = exp2(S), pi-packed into LDS (b64 writes, stride 72)
#pragma unroll
    for (int mf = 0; mf < 2; ++mf)
#pragma unroll
      for (int r = 0; r < 4; ++r) {
        const float p0 = EXP2F(s[mf][0][r]);
        const float p1 = EXP2F(s[mf][1][r]);
        const float p2 = EXP2F(s[mf][2][r]);
        const float p3 = EXP2F(s[mf][3][r]);
        u32x2 pk;
        pk.x = bfpack2(p0, p1);
        pk.y = bfpack2(p2, p3);
        *(u32x2*)&Pw[(mf * 16 + quad * 4 + r) * 72 + ln * 4] = pk;
      }

    // O += P V ; rowsum += P * ones  (within-wave LDS write->read)
#pragma unroll
    for (int kk = 0; kk < 2; ++kk)
#pragma unroll
      for (int mf = 0; mf < 2; ++mf) {
        bf16x8 pf = *(const bf16x8*)&Pw[(mf * 16 + ln) * 72 + kk * 32 + quad * 8];
        accS[mf] = __builtin_amdgcn_mfma_f32_16x16x32_bf16(pf, ones, accS[mf], 0, 0, 0);
#pragma unroll
        for (int df = 0; df < 2; ++df)
          acc[mf][df] = __builtin_amdgcn_mfma_f32_16x16x32_bf16(pf, vf[kk * 2 + df], acc[mf][df], 0, 0, 0);
      }

#pragma unroll
    for (int nf = 0; nf < 4; ++nf) kp[nf] += 64 * 1024;
#pragma unroll
    for (int df = 0; df < 2; ++df) vp[df] += 64;
  }

  // ---- cross-wave combine ----
  __syncthreads();
  f32x4* CA = (f32x4*)PwAll;             // [w][mf][df][lane] : 16 KB
  f32x4* CS = (f32x4*)&PwAll[8192];      // [w][mf][quad]     : 512 B
#pragma unroll
  for (int mf = 0; mf < 2; ++mf) {
#pragma unroll
    for (int df = 0; df < 2; ++df)
      CA[((wave * 2 + mf) * 2 + df) * 64 + lane] = acc[mf][df];
    if (ln == 0) CS[(wave * 2 + mf) * 4 + quad] = accS[mf];
  }
  __syncthreads();

  if (wave == 0) {
    const int j = ln & 7, chi = ln >> 3;
#pragma unroll
    for (int mf = 0; mf < 2; ++mf) {
      f32x4 l = CS[(0 + mf) * 4 + quad];
#pragma unroll
      for (int w = 1; w < 4; ++w) l += CS[((w * 2) + mf) * 4 + quad];
      f32x4 inv;
#pragma unroll
      for (int r = 0; r < 4; ++r) inv[r] = 1.0f / l[r];
#pragma unroll
      for (int df = 0; df < 2; ++df) {
        f32x4 t = CA[((0 + mf) * 2 + df) * 64 + lane];
#pragma unroll
        for (int w = 1; w < 4; ++w) t += CA[(((w * 2) + mf) * 2 + df) * 64 + lane];
        const int c = (h & 1) * 4 + df * 2 + chi;
#pragma unroll
        for (int r = 0; r < 4; ++r) {
          const int row = b * 1024 + q0 + mf * 16 + quad * 4 + r;
          const int cp  = c ^ ((quad * 4 + r) & 7);
          attn_sw[((size_t)(h >> 1) * 2048 + row) * 64 + cp * 8 + j] = bf16of(t[r] * inv[r]);
        }
      }
    }
  }
}

// ---------------------------------------------------------------------------
extern "C" void kernel_launch(void* const* d_in, const int* in_sizes, int n_in,
                              void* d_out, int out_size, void* d_ws, size_t ws_size,
                              hipStream_t stream) {
  (void)in_sizes; (void)n_in; (void)out_size; (void)ws_size;
  const float* query  = (const float*)d_in[0];
  const float* key    = (const float*)d_in[1];
  const float* value  = (const float*)d_in[2];
  const float* memory = (const float*)d_in[3];
  const float* Wq = (const float*)d_in[4];
  const float* bq = (const float*)d_in[5];
  const float* Wk = (const float*)d_in[6];
  const float* bk = (const float*)d_in[7];
  const float* Wv = (const float*)d_in[8];
  const float* bv = (const float*)d_in[9];
  const float* Wo = (const float*)d_in[10];
  const float* bo = (const float*)d_in[11];
  float* out = (float*)d_out;

  // workspace layout (76 MB)
  char* ws = (char*)d_ws;
  const size_t MB = 1024 * 1024;
  u16* query_sw = (u16*)(ws + 0 * MB);    //  4 MB (2048 rows)
  u16* key_sw   = (u16*)(ws + 4 * MB);    //  8 MB (4096 rows)
  u16* value_sw = (u16*)(ws + 12 * MB);   //  8 MB (4096 rows)
  u16* mem_sw   = (u16*)(ws + 20 * MB);   //  4 MB (2048 rows)
  u16* Wq_sw    = (u16*)(ws + 24 * MB);   //  2 MB
  u16* Wk_sw    = (u16*)(ws + 26 * MB);   //  2 MB
  u16* Wv_sw    = (u16*)(ws + 28 * MB);   //  2 MB
  u16* Wo_sw    = (u16*)(ws + 30 * MB);   //  2 MB
  u16* qp       = (u16*)(ws + 32 * MB);   //  4 MB
  u16* kcat     = (u16*)(ws + 36 * MB);   // 12 MB
  u16* vcat     = (u16*)(ws + 48 * MB);   // 12 MB
  u16* vT       = (u16*)(ws + 60 * MB);   // 12 MB
  u16* attn_sw  = (u16*)(ws + 72 * MB);   //  4 MB

  dim3 blk(256);
  prep_kernel<<<dim3(256), blk, 0, stream>>>(query, key, value, memory, Wq, Wk, Wv, Wo,
                                             query_sw, key_sw, value_sw, mem_sw,
                                             Wq_sw, Wk_sw, Wv_sw, Wo_sw);
  // qp + kcat + vcat in ONE launch (independent GEMMs, block-dispatched)
  proj3_kernel<<<dim3(112, 8), blk, 0, stream>>>(query_sw, key_sw, value_sw, mem_sw,
                                                 Wq_sw, bq, Wk_sw, bk, Wv_sw, bv,
                                                 qp, kcat, vcat);
  // vT (pi-permuted) for PV B-operand
  transpose_v_kernel<<<dim3(24, 64), blk, 0, stream>>>(vcat, vT);
  // attention -> swizzled panel-major A for final GEMM
  attn_kernel<<<dim3(2048), blk, 0, stream>>>(qp, kcat, vT, attn_sw);
  // out = attn Wo^T + bo
  gemm_out_kernel<<<dim3(32, 8), blk, 0, stream>>>(attn_sw, Wo_sw, bo, out);
}

// Round 6
// 235.507 us; speedup vs baseline: 1.4430x; 1.2013x over previous
//
#include <hip/hip_runtime.h>

// ---------------------------------------------------------------------------
// MemoryAttention: B=2 Q=1024 K=2048 M=1024 E=1024 H=32 HD=32
// Pipeline (4 launches):
//   prep  : fp32 -> bf16, panel-major XOR-swizzled layout for GEMM staging
//   proj3 : ONE launch = {qp, kcat} GEMMs + {vcat GEMM fused with per-(b,h)
//           pi-permuted transpose -> vT} (block-dispatch)
//   attn  : softmax(qp kcat^T) vT -> swizzled panel-major, 64 q-rows/wave
//   out   : attn Wo^T + bo (fp32 -> d_out)
// attn: 4 waves/block split 3072 keys; max-free softmax (scores pre-scaled by
// SCALE*LOG2E); rowsums via all-ones-B MFMA; parallel cross-wave combine.
// launch_bounds(256,3): VGPR cap ~170 (est use ~145) - NO spills (round-4
// lesson: overtight cap -> scratch traffic catastrophe).
// ---------------------------------------------------------------------------

typedef float  f32x4  __attribute__((ext_vector_type(4)));
typedef short  bf16x8 __attribute__((ext_vector_type(8)));
typedef unsigned int   u32;
typedef unsigned short u16;
typedef u32 u32x2 __attribute__((ext_vector_type(2)));
typedef u32 u32x4 __attribute__((ext_vector_type(4)));
typedef u16 u16x4 __attribute__((ext_vector_type(4)));

#define SCALE_  0.17677669529663687f   // 32^-0.5
#define LOG2E_  1.4426950408889634f

// raw v_exp_f32 (scores are |s|<~5: no denorm/inf handling needed)
#if defined(__has_builtin)
#  if __has_builtin(__builtin_amdgcn_exp2f)
#    define EXP2F(x) __builtin_amdgcn_exp2f(x)
#  endif
#endif
#ifndef EXP2F
#  define EXP2F(x) __builtin_exp2f(x)
#endif

static __device__ __forceinline__ u32 bfpack2(float lo, float hi) {
  u32 a = __builtin_bit_cast(u32, lo) + 0x8000u;
  u32 b = __builtin_bit_cast(u32, hi) + 0x8000u;
  return __builtin_amdgcn_perm(b, a, 0x07060302u);
}
static __device__ __forceinline__ u16 bf16of(float x) {
  return (u16)((__builtin_bit_cast(u32, x) + 0x8000u) >> 16);
}
static __device__ __forceinline__ void gld_lds16(const u16* g, u16* l) {
  __builtin_amdgcn_global_load_lds(
      (const __attribute__((address_space(1))) void*)g,
      (__attribute__((address_space(3))) void*)l, 16, 0, 0);
}

// ---------------------------------------------------------------------------
// prep: fp32 -> bf16 swizzled panel-major. kt-major / row-minor mapping:
// each iteration writes 4 KB fully contiguous per 256 threads.
// ---------------------------------------------------------------------------
__global__ __launch_bounds__(256)
void prep_kernel(const float* __restrict__ q, const float* __restrict__ k,
                 const float* __restrict__ v, const float* __restrict__ m,
                 const float* __restrict__ wq, const float* __restrict__ wk,
                 const float* __restrict__ wv, const float* __restrict__ wo,
                 u16* qs, u16* ks, u16* vs, u16* ms,
                 u16* wqs, u16* wks, u16* wvs, u16* wos) {
  const int bid = blockIdx.x;
  const float* src; u16* dst; int R, r0;
  if (bid < 32)       { src = q;  dst = qs;  R = 2048; r0 = bid * 64; }
  else if (bid < 96)  { src = k;  dst = ks;  R = 4096; r0 = (bid - 32) * 64; }
  else if (bid < 160) { src = v;  dst = vs;  R = 4096; r0 = (bid - 96) * 64; }
  else if (bid < 192) { src = m;  dst = ms;  R = 2048; r0 = (bid - 160) * 64; }
  else if (bid < 208) { src = wq; dst = wqs; R = 1024; r0 = (bid - 192) * 64; }
  else if (bid < 224) { src = wk; dst = wks; R = 1024; r0 = (bid - 208) * 64; }
  else if (bid < 240) { src = wv; dst = wvs; R = 1024; r0 = (bid - 224) * 64; }
  else                { src = wo; dst = wos; R = 1024; r0 = (bid - 240) * 64; }

  for (int i = 0; i < 32; ++i) {
    const int idx = i * 256 + threadIdx.x;    // 16 kt x 64 rows x 8 c
    const int kt  = idx >> 9;
    const int rem = idx & 511;
    const int row = rem >> 3;
    const int c   = rem & 7;
    const float* s = src + (size_t)(r0 + row) * 1024 + kt * 64 + c * 8;
    f32x4 a = *(const f32x4*)s, b = *(const f32x4*)(s + 4);
    u32x4 p;
    p.x = bfpack2(a.x, a.y); p.y = bfpack2(a.z, a.w);
    p.z = bfpack2(b.x, b.y); p.w = bfpack2(b.z, b.w);
    *(u32x4*)&dst[((size_t)kt * R + r0 + row) * 64 + ((c ^ (row & 7)) << 3)] = p;
  }
}

// ---------------------------------------------------------------------------
// GEMM core: acc[m,n] = sum_k A[m,k]*W[n,k]; MT x 128 tile, BK=64, 4 waves,
// global_load_lds staging, XOR-swizzled LDS (2-way banks = free).
// Ends with __syncthreads() -> caller may reuse As/Bs.
// ---------------------------------------------------------------------------
template <int MT>
static __device__ __forceinline__
void gemm_core(const u16* __restrict__ Abase, size_t row0, int RA,
               const u16* __restrict__ Wsw, int bn,
               u16* As, u16* Bs, f32x4 acc[][4]) {
  constexpr int MI = MT / 32;
  const int tid  = threadIdx.x;
  const int lane = tid & 63;
  const int wave = tid >> 6;
  const int ln   = lane & 15;
  const int quad = lane >> 4;
  const int wm   = wave >> 1;
  const int wn   = wave & 1;

#pragma unroll
  for (int i = 0; i < MI; ++i)
#pragma unroll
    for (int j = 0; j < 4; ++j)
      acc[i][j] = (f32x4){0.f, 0.f, 0.f, 0.f};

  for (int kt = 0; kt < 16; ++kt) {
    const u16* Ag = Abase + ((size_t)kt * RA + row0) * 64;
    const u16* Bg = Wsw + ((size_t)kt * 1024 + bn * 128) * 64;
#pragma unroll
    for (int r = 0; r < MI; ++r) {
      const int ii = wave * MI + r;
      gld_lds16(Ag + ii * 512 + lane * 8, &As[ii * 512]);
    }
#pragma unroll
    for (int r = 0; r < 4; ++r) {
      const int ii = wave * 4 + r;
      gld_lds16(Bg + ii * 512 + lane * 8, &Bs[ii * 512]);
    }
    __syncthreads();

#pragma unroll
    for (int kk = 0; kk < 2; ++kk) {
      bf16x8 af[MI], bfr[4];
#pragma unroll
      for (int mi = 0; mi < MI; ++mi) {
        const int row = wm * (MI * 16) + mi * 16 + ln;
        af[mi] = *(const bf16x8*)&As[row * 64 + (((kk * 4 + quad) ^ (ln & 7)) << 3)];
      }
#pragma unroll
      for (int ni = 0; ni < 4; ++ni) {
        const int row = wn * 64 + ni * 16 + ln;
        bfr[ni] = *(const bf16x8*)&Bs[row * 64 + (((kk * 4 + quad) ^ (ln & 7)) << 3)];
      }
#pragma unroll
      for (int mi = 0; mi < MI; ++mi)
#pragma unroll
        for (int ni = 0; ni < 4; ++ni)
          acc[mi][ni] = __builtin_amdgcn_mfma_f32_16x16x32_bf16(af[mi], bfr[ni], acc[mi][ni], 0, 0, 0);
    }
    __syncthreads();
  }
}

// ---------------------------------------------------------------------------
// proj3: one launch. bx<16: qp (bf16 row-major, pre-scaled). 16..63: kcat
// (bf16 row-major). 64..111: vcat computed and written DIRECTLY as vT
// (per-(b,h) transpose, key axis pi-permuted) via LDS re-tile.
// ---------------------------------------------------------------------------
__global__ __launch_bounds__(256)
void proj3_kernel(const u16* __restrict__ query_sw,
                  const u16* __restrict__ key_sw,
                  const u16* __restrict__ value_sw,
                  const u16* __restrict__ mem_sw,
                  const u16* __restrict__ Wq_sw, const float* __restrict__ bq,
                  const u16* __restrict__ Wk_sw, const float* __restrict__ bk,
                  const u16* __restrict__ Wv_sw, const float* __restrict__ bv,
                  u16* qp, u16* kcat, u16* vT) {
  __shared__ u16 SH[16896];            // As(8192) + Bs(8192) | T(128x132)
  u16* As = SH;
  u16* Bs = SH + 8192;

  const int tid  = threadIdx.x;
  const int lane = tid & 63;
  const int wave = tid >> 6;
  const int ln   = lane & 15;
  const int quad = lane >> 4;
  const int wm   = wave >> 1;
  const int wn   = wave & 1;
  const int bx = blockIdx.x, bn = blockIdx.y;

  const u16* Abase; size_t row0; int RA, bm, bb, l0;
  const u16* W; const float* bias;

  if (bx < 16) {
    bm = bx; Abase = query_sw; row0 = (size_t)bm * 128; RA = 2048;
    W = Wq_sw; bias = bq; bb = 0; l0 = 0;
  } else {
    const int bxx = (bx < 64) ? (bx - 16) : (bx - 64);
    bm = bxx;
    const int gr0 = bxx * 128;
    bb = gr0 / 3072;
    l0 = gr0 - bb * 3072;
    const u16* seq = (bx < 64) ? key_sw : value_sw;
    if (l0 < 2048) { Abase = seq;    row0 = (size_t)bb * 2048 + l0;          RA = 4096; }
    else           { Abase = mem_sw; row0 = (size_t)bb * 1024 + (l0 - 2048); RA = 2048; }
    if (bx < 64) { W = Wk_sw; bias = bk; }
    else         { W = Wv_sw; bias = bv; }
  }

  f32x4 acc[4][4];
  gemm_core<128>(Abase, row0, RA, W, bn, As, Bs, acc);

  if (bx < 64) {
    // row-major bf16 epilogue (qp pre-scaled by SCALE*LOG2E)
    u16* C = (bx < 16) ? qp : kcat;
    const float scale = (bx < 16) ? (SCALE_ * LOG2E_) : 1.0f;
#pragma unroll
    for (int ni = 0; ni < 4; ++ni) {
      const int gc = bn * 128 + wn * 64 + ni * 16 + ln;
      const float bval = bias[gc];
#pragma unroll
      for (int mi = 0; mi < 4; ++mi) {
        const int gr = bm * 128 + wm * 64 + mi * 16 + quad * 4;
#pragma unroll
        for (int r = 0; r < 4; ++r)
          C[(size_t)(gr + r) * 1024 + gc] = bf16of((acc[mi][ni][r] + bval) * scale);
      }
    }
  } else {
    // transpose epilogue -> vT[(b,h,d), pi-permuted key]
    u16* T = SH;                       // 128 x 132 (pad -> 2-way banks)
#pragma unroll
    for (int ni = 0; ni < 4; ++ni) {
      const int fl = wn * 64 + ni * 16 + ln;
      const float bval = bias[bn * 128 + fl];
#pragma unroll
      for (int mi = 0; mi < 4; ++mi) {
        const int kl = wm * 64 + mi * 16 + quad * 4;
#pragma unroll
        for (int r = 0; r < 4; ++r)
          T[(kl + r) * 132 + fl] = bf16of(acc[mi][ni][r] + bval);
      }
    }
    __syncthreads();
    const int fr = tid >> 1;           // f_local 0..127
    const int ch = tid & 1;            // which 64-key chunk
    const int fg = bn * 128 + fr;      // global feature
    const size_t rowg = ((size_t)bb * 32 + (fg >> 5)) * 32 + (fg & 31);
    u16* dstrow = vT + rowg * 3072 + l0 + ch * 64;
#pragma unroll
    for (int x = 0; x < 16; ++x) {
      u16x4 v;
      v.x = T[(ch * 64 + x +  0) * 132 + fr];
      v.y = T[(ch * 64 + x + 16) * 132 + fr];
      v.z = T[(ch * 64 + x + 32) * 132 + fr];
      v.w = T[(ch * 64 + x + 48) * 132 + fr];
      *(u16x4*)&dstrow[x * 4] = v;
    }
  }
}

// ---------------------------------------------------------------------------
// out = attn Wo^T + bo  (fp32 out)
// ---------------------------------------------------------------------------
__global__ __launch_bounds__(256)
void gemm_out_kernel(const u16* __restrict__ attn_sw,
                     const u16* __restrict__ Wo_sw,
                     const float* __restrict__ bo,
                     float* __restrict__ out) {
  __shared__ u16 As[64 * 64];
  __shared__ u16 Bs[128 * 64];
  const int tid  = threadIdx.x;
  const int lane = tid & 63;
  const int wave = tid >> 6;
  const int ln   = lane & 15;
  const int quad = lane >> 4;
  const int wm   = wave >> 1;
  const int wn   = wave & 1;
  const int bm = blockIdx.x, bn = blockIdx.y;

  f32x4 acc[2][4];
  gemm_core<64>(attn_sw, (size_t)bm * 64, 2048, Wo_sw, bn, As, Bs, acc);

#pragma unroll
  for (int ni = 0; ni < 4; ++ni) {
    const int gc = bn * 128 + wn * 64 + ni * 16 + ln;
    const float bval = bo[gc];
#pragma unroll
    for (int mi = 0; mi < 2; ++mi) {
      const int gr = bm * 64 + wm * 32 + mi * 16 + quad * 4;
#pragma unroll
      for (int r = 0; r < 4; ++r)
        out[(size_t)(gr + r) * 1024 + gc] = acc[mi][ni][r] + bval;
    }
  }
}

// ---------------------------------------------------------------------------
// Attention: block = (bh, 64 q-rows), 4 waves split 3072 keys (12 chunks of
// 64 each). 64 q/wave (4 mf frags): 4 independent QK->exp chains per chunk
// (ILP), half the K/V L2 traffic of the 32-q design. Max-free softmax,
// raw v_exp; rowsums via all-ones-B MFMA; parallel cross-wave combine
// (wave w reduces mf=w). Grid: bid = qt*64+bh -> XCD pins K/V by bh%8.
// ---------------------------------------------------------------------------
__global__ __launch_bounds__(256, 3)
void attn_kernel(const u16* __restrict__ qp,
                 const u16* __restrict__ kcat,
                 const u16* __restrict__ vTp,
                 u16* __restrict__ attn_sw) {
  __shared__ u16 PwAll[4 * 64 * 72];   // 36864 B; reused for combine

  const int tid  = threadIdx.x;
  const int lane = tid & 63;
  const int wave = tid >> 6;
  const int ln   = lane & 15;
  const int quad = lane >> 4;
  const int bid  = blockIdx.x;
  const int bh   = bid & 63;
  const int qt   = bid >> 6;           // 0..15
  const int b    = bh >> 5;
  const int h    = bh & 31;
  const int q0   = qt * 64;

  bf16x8 qf[4];
#pragma unroll
  for (int mf = 0; mf < 4; ++mf)
    qf[mf] = *(const bf16x8*)&qp[(size_t)(b * 1024 + q0 + mf * 16 + ln) * 1024 + h * 32 + quad * 8];

  f32x4 acc[4][2], accS[4];
#pragma unroll
  for (int mf = 0; mf < 4; ++mf) {
    accS[mf] = (f32x4){0.f, 0.f, 0.f, 0.f};
#pragma unroll
    for (int df = 0; df < 2; ++df) acc[mf][df] = (f32x4){0.f, 0.f, 0.f, 0.f};
  }
  bf16x8 ones;
#pragma unroll
  for (int i = 0; i < 8; ++i) ones[i] = (short)0x3F80;   // bf16 1.0

  const u16* kbase = kcat + (size_t)(b * 3072) * 1024 + h * 32;
  const u16* vbase = vTp + (size_t)(bh * 32) * 3072;
  u16* Pw = &PwAll[wave * (64 * 72)];

  const u16* kp[4];
  const u16* vp[2];
#pragma unroll
  for (int nf = 0; nf < 4; ++nf)
    kp[nf] = kbase + (size_t)(wave * 768 + nf * 16 + ln) * 1024 + quad * 8;
#pragma unroll
  for (int df = 0; df < 2; ++df)
    vp[df] = vbase + (size_t)(df * 16 + ln) * 3072 + wave * 768 + quad * 8;

  for (int ci = 0; ci < 12; ++ci) {
    bf16x8 kf[4], vf[4];
#pragma unroll
    for (int nf = 0; nf < 4; ++nf)
      kf[nf] = *(const bf16x8*)kp[nf];
#pragma unroll
    for (int kk = 0; kk < 2; ++kk)
#pragma unroll
      for (int df = 0; df < 2; ++df)
        vf[kk * 2 + df] = *(const bf16x8*)(vp[df] + kk * 32);

    // per-mf: QK MFMA -> exp -> pi-packed LDS write (4 independent chains)
#pragma unroll
    for (int mf = 0; mf < 4; ++mf) {
      f32x4 s[4];
#pragma unroll
      for (int nf = 0; nf < 4; ++nf)
        s[nf] = __builtin_amdgcn_mfma_f32_16x16x32_bf16(qf[mf], kf[nf],
                                                        (f32x4){0.f, 0.f, 0.f, 0.f}, 0, 0, 0);
#pragma unroll
      for (int r = 0; r < 4; ++r) {
        const float p0 = EXP2F(s[0][r]);
        const float p1 = EXP2F(s[1][r]);
        const float p2 = EXP2F(s[2][r]);
        const float p3 = EXP2F(s[3][r]);
        u32x2 pk;
        pk.x = bfpack2(p0, p1);
        pk.y = bfpack2(p2, p3);
        *(u32x2*)&Pw[(mf * 16 + quad * 4 + r) * 72 + ln * 4] = pk;
      }
    }

    // O += P V ; rowsum += P * ones  (within-wave LDS write->read)
#pragma unroll
    for (int kk = 0; kk < 2; ++kk)
#pragma unroll
      for (int mf = 0; mf < 4; ++mf) {
        bf16x8 pf = *(const bf16x8*)&Pw[(mf * 16 + ln) * 72 + kk * 32 + quad * 8];
        accS[mf] = __builtin_amdgcn_mfma_f32_16x16x32_bf16(pf, ones, accS[mf], 0, 0, 0);
#pragma unroll
        for (int df = 0; df < 2; ++df)
          acc[mf][df] = __builtin_amdgcn_mfma_f32_16x16x32_bf16(pf, vf[kk * 2 + df], acc[mf][df], 0, 0, 0);
      }

#pragma unroll
    for (int nf = 0; nf < 4; ++nf) kp[nf] += 64 * 1024;
#pragma unroll
    for (int df = 0; df < 2; ++df) vp[df] += 64;
  }

  // ---- cross-wave combine (parallel: wave w reduces mf = w) ----
  __syncthreads();
  f32x4* CA = (f32x4*)PwAll;             // [w][mf][df][lane] : 32 KB
  f32x4* CS = (f32x4*)&PwAll[16384];     // [w][mf][quad]     : 1 KB
#pragma unroll
  for (int mf = 0; mf < 4; ++mf) {
#pragma unroll
    for (int df = 0; df < 2; ++df)
      CA[((wave * 4 + mf) * 2 + df) * 64 + lane] = acc[mf][df];
    if (ln == 0) CS[(wave * 4 + mf) * 4 + quad] = accS[mf];
  }
  __syncthreads();

  {
    const int mf = wave;
    const int j = ln & 7, chi = ln >> 3;
    f32x4 l = CS[mf * 4 + quad];
#pragma unroll
    for (int w = 1; w < 4; ++w) l += CS[((w * 4) + mf) * 4 + quad];
    f32x4 inv;
#pragma unroll
    for (int r = 0; r < 4; ++r) inv[r] = 1.0f / l[r];
#pragma unroll
    for (int df = 0; df < 2; ++df) {
      f32x4 t = CA[(mf * 2 + df) * 64 + lane];
#pragma unroll
      for (int w = 1; w < 4; ++w) t += CA[(((w * 4) + mf) * 2 + df) * 64 + lane];
      const int c = (h & 1) * 4 + df * 2 + chi;
#pragma unroll
      for (int r = 0; r < 4; ++r) {
        const int row = b * 1024 + q0 + mf * 16 + quad * 4 + r;
        const int cp  = c ^ ((quad * 4 + r) & 7);
        attn_sw[((size_t)(h >> 1) * 2048 + row) * 64 + cp * 8 + j] = bf16of(t[r] * inv[r]);
      }
    }
  }
}

// ---------------------------------------------------------------------------
extern "C" void kernel_launch(void* const* d_in, const int* in_sizes, int n_in,
                              void* d_out, int out_size, void* d_ws, size_t ws_size,
                              hipStream_t stream) {
  (void)in_sizes; (void)n_in; (void)out_size; (void)ws_size;
  const float* query  = (const float*)d_in[0];
  const float* key    = (const float*)d_in[1];
  const float* value  = (const float*)d_in[2];
  const float* memory = (const float*)d_in[3];
  const float* Wq = (const float*)d_in[4];
  const float* bq = (const float*)d_in[5];
  const float* Wk = (const float*)d_in[6];
  const float* bk = (const float*)d_in[7];
  const float* Wv = (const float*)d_in[8];
  const float* bv = (const float*)d_in[9];
  const float* Wo = (const float*)d_in[10];
  const float* bo = (const float*)d_in[11];
  float* out = (float*)d_out;

  // workspace layout (64 MB)
  char* ws = (char*)d_ws;
  const size_t MB = 1024 * 1024;
  u16* query_sw = (u16*)(ws + 0 * MB);    //  4 MB (2048 rows)
  u16* key_sw   = (u16*)(ws + 4 * MB);    //  8 MB (4096 rows)
  u16* value_sw = (u16*)(ws + 12 * MB);   //  8 MB (4096 rows)
  u16* mem_sw   = (u16*)(ws + 20 * MB);   //  4 MB (2048 rows)
  u16* Wq_sw    = (u16*)(ws + 24 * MB);   //  2 MB
  u16* Wk_sw    = (u16*)(ws + 26 * MB);   //  2 MB
  u16* Wv_sw    = (u16*)(ws + 28 * MB);   //  2 MB
  u16* Wo_sw    = (u16*)(ws + 30 * MB);   //  2 MB
  u16* qp       = (u16*)(ws + 32 * MB);   //  4 MB
  u16* kcat     = (u16*)(ws + 36 * MB);   // 12 MB
  u16* vT       = (u16*)(ws + 48 * MB);   // 12 MB
  u16* attn_sw  = (u16*)(ws + 60 * MB);   //  4 MB

  dim3 blk(256);
  prep_kernel<<<dim3(256), blk, 0, stream>>>(query, key, value, memory, Wq, Wk, Wv, Wo,
                                             query_sw, key_sw, value_sw, mem_sw,
                                             Wq_sw, Wk_sw, Wv_sw, Wo_sw);
  // qp + kcat + vT(=transposed vcat) in ONE launch
  proj3_kernel<<<dim3(112, 8), blk, 0, stream>>>(query_sw, key_sw, value_sw, mem_sw,
                                                 Wq_sw, bq, Wk_sw, bk, Wv_sw, bv,
                                                 qp, kcat, vT);
  // attention -> swizzled panel-major A for final GEMM (1024 blocks, 64 q/blk)
  attn_kernel<<<dim3(1024), blk, 0, stream>>>(qp, kcat, vT, attn_sw);
  // out = attn Wo^T + bo
  gemm_out_kernel<<<dim3(32, 8), blk, 0, stream>>>(attn_sw, Wo_sw, bo, out);
}